// Round 1
// baseline (1004.325 us; speedup 1.0000x reference)
//
#include <hip/hip_runtime.h>
#include <math.h>

#define B_SZ 16
#define D_CH 512
#define U_LEN 2048
#define R_LEN 512
#define T_LEN 2560
#define KS 31
#define CS 30

__device__ __forceinline__ float sigmoidf_(float x) { return 1.0f / (1.0f + expf(-x)); }

// K1: pointwise conv (D->2D) + GLU. A rows: q = b*T + t ordering. Output y in (B,T,D).
__global__ __launch_bounds__(256) void k1_gemm_glu(
    const float* __restrict__ utt, const float* __restrict__ rc,
    const float* __restrict__ w1, const float* __restrict__ b1,
    float* __restrict__ y)
{
    __shared__ float sA[32 * 64];   // [k][m]
    __shared__ float sBa[32 * 64];  // [k][n]
    __shared__ float sBg[32 * 64];  // [k][n]
    const int tid = threadIdx.x;
    const int d0 = blockIdx.y * 64;
    const int b  = blockIdx.x / 40;          // T_LEN/64 = 40 tiles per b
    const int t0 = (blockIdx.x % 40) * 64;
    const float* abase;
    int rowoff;
    if (t0 < R_LEN) { abase = rc;  rowoff = t0 * B_SZ + b; }
    else            { abase = utt; rowoff = (t0 - R_LEN) * B_SZ + b; }

    const int tx = tid & 15, ty = tid >> 4;
    float acc_a[4][4] = {{0.f,0.f,0.f,0.f},{0.f,0.f,0.f,0.f},{0.f,0.f,0.f,0.f},{0.f,0.f,0.f,0.f}};
    float acc_g[4][4] = {{0.f,0.f,0.f,0.f},{0.f,0.f,0.f,0.f},{0.f,0.f,0.f,0.f},{0.f,0.f,0.f,0.f}};

    const int m = tid >> 2;  // 0..63 (row for staging)
    const int f = tid & 3;   // 0..3

    for (int kc = 0; kc < 512; kc += 32) {
        __syncthreads();
        {   // stage A tile: 64 rows x 32 k, transposed into [k][m]
            const float* src = abase + (size_t)(rowoff + m * B_SZ) * D_CH + kc;
            float4 v0 = ((const float4*)src)[f];
            float4 v1 = ((const float4*)src)[f + 4];
            int k0 = 4 * f, k1 = 4 * (f + 4);
            sA[(k0+0)*64+m] = v0.x; sA[(k0+1)*64+m] = v0.y; sA[(k0+2)*64+m] = v0.z; sA[(k0+3)*64+m] = v0.w;
            sA[(k1+0)*64+m] = v1.x; sA[(k1+1)*64+m] = v1.y; sA[(k1+2)*64+m] = v1.z; sA[(k1+3)*64+m] = v1.w;
        }
        {   // stage B tiles (a-half rows d0+n, g-half rows 512+d0+n)
            const float* srca = w1 + (size_t)(d0 + m) * 512 + kc;
            const float* srcg = w1 + (size_t)(512 + d0 + m) * 512 + kc;
            float4 a0 = ((const float4*)srca)[f];
            float4 a1 = ((const float4*)srca)[f + 4];
            float4 g0 = ((const float4*)srcg)[f];
            float4 g1 = ((const float4*)srcg)[f + 4];
            int k0 = 4 * f, k1 = 4 * (f + 4);
            sBa[(k0+0)*64+m] = a0.x; sBa[(k0+1)*64+m] = a0.y; sBa[(k0+2)*64+m] = a0.z; sBa[(k0+3)*64+m] = a0.w;
            sBa[(k1+0)*64+m] = a1.x; sBa[(k1+1)*64+m] = a1.y; sBa[(k1+2)*64+m] = a1.z; sBa[(k1+3)*64+m] = a1.w;
            sBg[(k0+0)*64+m] = g0.x; sBg[(k0+1)*64+m] = g0.y; sBg[(k0+2)*64+m] = g0.z; sBg[(k0+3)*64+m] = g0.w;
            sBg[(k1+0)*64+m] = g1.x; sBg[(k1+1)*64+m] = g1.y; sBg[(k1+2)*64+m] = g1.z; sBg[(k1+3)*64+m] = g1.w;
        }
        __syncthreads();
        #pragma unroll
        for (int k = 0; k < 32; ++k) {
            float4 av  = *(const float4*)&sA [k * 64 + ty * 4];
            float4 bav = *(const float4*)&sBa[k * 64 + tx * 4];
            float4 bgv = *(const float4*)&sBg[k * 64 + tx * 4];
            float am[4] = {av.x, av.y, av.z, av.w};
            float ba[4] = {bav.x, bav.y, bav.z, bav.w};
            float bg[4] = {bgv.x, bgv.y, bgv.z, bgv.w};
            #pragma unroll
            for (int i = 0; i < 4; ++i) {
                #pragma unroll
                for (int j = 0; j < 4; ++j) {
                    acc_a[i][j] = fmaf(am[i], ba[j], acc_a[i][j]);
                    acc_g[i][j] = fmaf(am[i], bg[j], acc_g[i][j]);
                }
            }
        }
    }
    // epilogue: bias + GLU, write y (B,T,D), coalesced float4 along d
    float biasa[4], biasg[4];
    #pragma unroll
    for (int j = 0; j < 4; ++j) {
        biasa[j] = b1[d0 + tx * 4 + j];
        biasg[j] = b1[512 + d0 + tx * 4 + j];
    }
    #pragma unroll
    for (int i = 0; i < 4; ++i) {
        int t = t0 + ty * 4 + i;
        float4 o;
        float a0 = acc_a[i][0] + biasa[0], g0 = acc_g[i][0] + biasg[0];
        float a1 = acc_a[i][1] + biasa[1], g1 = acc_g[i][1] + biasg[1];
        float a2 = acc_a[i][2] + biasa[2], g2 = acc_g[i][2] + biasg[2];
        float a3 = acc_a[i][3] + biasa[3], g3 = acc_g[i][3] + biasg[3];
        o.x = a0 * sigmoidf_(g0);
        o.y = a1 * sigmoidf_(g1);
        o.z = a2 * sigmoidf_(g2);
        o.w = a3 * sigmoidf_(g3);
        *(float4*)(y + ((size_t)b * T_LEN + t) * D_CH + d0 + tx * 4) = o;
    }
}

// K2: depthwise conv over utterance path + swish, write z (T,B,D) at t = R+u
__global__ __launch_bounds__(256) void k2_dw_utt(
    const float* __restrict__ y, const float* __restrict__ cache,
    const float* __restrict__ wd, const float* __restrict__ bd,
    float* __restrict__ z)
{
    __shared__ float sy[64 * 97];  // [d_local][p_local], window 94, pad to 97
    __shared__ float sw[64 * 31];
    const int tid = threadIdx.x;
    const int u0 = blockIdx.x * 64;
    const int d0 = blockIdx.y * 64;
    const int b  = blockIdx.z;

    // stage window: pad-index p = u0 + r, r in [0,94). p<30 -> cache, else y t=512+p-30
    for (int idx = tid; idx < 94 * 16; idx += 256) {
        int r  = idx >> 4;    // 0..93
        int c4 = idx & 15;    // 0..15 (float4 along d)
        int p  = u0 + r;
        float4 v;
        if (p < CS) {
            int dg = d0 + c4 * 4;
            v.x = cache[((size_t)b * D_CH + dg + 0) * CS + p];
            v.y = cache[((size_t)b * D_CH + dg + 1) * CS + p];
            v.z = cache[((size_t)b * D_CH + dg + 2) * CS + p];
            v.w = cache[((size_t)b * D_CH + dg + 3) * CS + p];
        } else {
            int t = R_LEN + p - CS;
            v = *(const float4*)(y + ((size_t)b * T_LEN + t) * D_CH + d0 + c4 * 4);
        }
        int dl = c4 * 4;
        sy[(dl+0)*97 + r] = v.x;
        sy[(dl+1)*97 + r] = v.y;
        sy[(dl+2)*97 + r] = v.z;
        sy[(dl+3)*97 + r] = v.w;
    }
    for (int idx = tid; idx < 64 * 31; idx += 256) {
        int d = idx / 31, k = idx - d * 31;
        sw[d * 31 + k] = wd[(size_t)(d0 + d) * KS + k];
    }
    __syncthreads();

    const int dl   = tid & 63;
    const int useg = (tid >> 6) * 16;
    float win[46];
    #pragma unroll
    for (int p = 0; p < 46; ++p) win[p] = sy[dl * 97 + useg + p];
    float bias = bd[d0 + dl];
    float acc[16];
    #pragma unroll
    for (int i = 0; i < 16; ++i) acc[i] = bias;
    for (int k = 0; k < 31; ++k) {
        float w = sw[dl * 31 + k];
        #pragma unroll
        for (int i = 0; i < 16; ++i) acc[i] = fmaf(w, win[k + i], acc[i]);
    }
    #pragma unroll
    for (int i = 0; i < 16; ++i) {
        float v = acc[i];
        v = v * sigmoidf_(v - 1.0f);
        int u = u0 + useg + i;
        z[((size_t)(R_LEN + u) * B_SZ + b) * D_CH + d0 + dl] = v;
    }
}

// K2rc: right-context chunked depthwise conv + swish, write z at t = i*8+j
__global__ __launch_bounds__(256) void k2_dw_rc(
    const float* __restrict__ y, const float* __restrict__ wd, const float* __restrict__ bd,
    float* __restrict__ z)
{
    __shared__ float sy[38 * 256]; // [frame][d_local]
    const int tid = threadIdx.x;
    const int i  = blockIdx.x;           // chunk 0..63
    const int b  = blockIdx.y;
    const int dbase = blockIdx.z * 256;

    for (int idx = tid; idx < 38 * 64; idx += 256) {
        int r  = idx >> 6;   // frame 0..37
        int c4 = idx & 63;
        int t = (r < CS) ? (R_LEN + 32 * i + 2 + r) : (8 * i + (r - CS));
        *(float4*)&sy[r * 256 + c4 * 4] =
            *(const float4*)(y + ((size_t)b * T_LEN + t) * D_CH + dbase + c4 * 4);
    }
    __syncthreads();

    const int dd = dbase + tid;
    float wr[31];
    #pragma unroll
    for (int k = 0; k < 31; ++k) wr[k] = wd[(size_t)dd * KS + k];
    float bias = bd[dd];
    #pragma unroll
    for (int j = 0; j < 8; ++j) {
        float acc = bias;
        #pragma unroll
        for (int k = 0; k < 31; ++k) acc = fmaf(wr[k], sy[(j + k) * 256 + tid], acc);
        float v = acc * sigmoidf_(acc - 1.0f);
        z[((size_t)(i * 8 + j) * B_SZ + b) * D_CH + dd] = v;
    }
}

// K3: pointwise conv w2 (D->D) + bias, scatter to final outputs (utt first, then rc)
__global__ __launch_bounds__(256) void k3_gemm2(
    const float* __restrict__ z, const float* __restrict__ w2, const float* __restrict__ b2,
    float* __restrict__ out)
{
    __shared__ float sA[32 * 64];
    __shared__ float sB[32 * 64];
    const int tid = threadIdx.x;
    const int d0 = blockIdx.y * 64;
    const int b  = blockIdx.x / 40;
    const int t0 = (blockIdx.x % 40) * 64;

    const int tx = tid & 15, ty = tid >> 4;
    float acc[4][4] = {{0.f,0.f,0.f,0.f},{0.f,0.f,0.f,0.f},{0.f,0.f,0.f,0.f},{0.f,0.f,0.f,0.f}};
    const int m = tid >> 2;
    const int f = tid & 3;

    for (int kc = 0; kc < 512; kc += 32) {
        __syncthreads();
        {
            const float* src = z + ((size_t)(t0 + m) * B_SZ + b) * D_CH + kc;
            float4 v0 = ((const float4*)src)[f];
            float4 v1 = ((const float4*)src)[f + 4];
            int k0 = 4 * f, k1 = 4 * (f + 4);
            sA[(k0+0)*64+m] = v0.x; sA[(k0+1)*64+m] = v0.y; sA[(k0+2)*64+m] = v0.z; sA[(k0+3)*64+m] = v0.w;
            sA[(k1+0)*64+m] = v1.x; sA[(k1+1)*64+m] = v1.y; sA[(k1+2)*64+m] = v1.z; sA[(k1+3)*64+m] = v1.w;
        }
        {
            const float* src = w2 + (size_t)(d0 + m) * 512 + kc;
            float4 v0 = ((const float4*)src)[f];
            float4 v1 = ((const float4*)src)[f + 4];
            int k0 = 4 * f, k1 = 4 * (f + 4);
            sB[(k0+0)*64+m] = v0.x; sB[(k0+1)*64+m] = v0.y; sB[(k0+2)*64+m] = v0.z; sB[(k0+3)*64+m] = v0.w;
            sB[(k1+0)*64+m] = v1.x; sB[(k1+1)*64+m] = v1.y; sB[(k1+2)*64+m] = v1.z; sB[(k1+3)*64+m] = v1.w;
        }
        __syncthreads();
        #pragma unroll
        for (int k = 0; k < 32; ++k) {
            float4 av = *(const float4*)&sA[k * 64 + ty * 4];
            float4 bv = *(const float4*)&sB[k * 64 + tx * 4];
            float am[4] = {av.x, av.y, av.z, av.w};
            float bn[4] = {bv.x, bv.y, bv.z, bv.w};
            #pragma unroll
            for (int i = 0; i < 4; ++i) {
                #pragma unroll
                for (int j = 0; j < 4; ++j) acc[i][j] = fmaf(am[i], bn[j], acc[i][j]);
            }
        }
    }
    float bias[4];
    #pragma unroll
    for (int j = 0; j < 4; ++j) bias[j] = b2[d0 + tx * 4 + j];
    #pragma unroll
    for (int i = 0; i < 4; ++i) {
        int t = t0 + ty * 4 + i;
        float4 o;
        o.x = acc[i][0] + bias[0];
        o.y = acc[i][1] + bias[1];
        o.z = acc[i][2] + bias[2];
        o.w = acc[i][3] + bias[3];
        size_t off;
        if (t < R_LEN) off = (size_t)U_LEN * B_SZ * D_CH + ((size_t)t * B_SZ + b) * D_CH;       // rc_final
        else           off = ((size_t)(t - R_LEN) * B_SZ + b) * D_CH;                           // utt_final
        *(float4*)(out + off + d0 + tx * 4) = o;
    }
}

// K4: new_cache = GLU-utt frames 2018..2047 -> out[(b,d,j)] at offset 20971520
__global__ __launch_bounds__(256) void k4_cache(const float* __restrict__ y, float* __restrict__ out)
{
    int tid = blockIdx.x * 256 + threadIdx.x;  // 16*30*512 total, d fastest
    int d = tid & 511;
    int j = (tid >> 9) % 30;
    int b = tid / (30 * 512);
    float v = y[((size_t)b * T_LEN + (R_LEN + 2018 + j)) * D_CH + d];
    out[(size_t)20971520 + ((size_t)b * D_CH + d) * CS + j] = v;
}

extern "C" void kernel_launch(void* const* d_in, const int* in_sizes, int n_in,
                              void* d_out, int out_size, void* d_ws, size_t ws_size,
                              hipStream_t stream)
{
    const float* utt   = (const float*)d_in[0];
    const float* rc    = (const float*)d_in[1];
    const float* cache = (const float*)d_in[2];
    const float* w1    = (const float*)d_in[3];
    const float* b1    = (const float*)d_in[4];
    const float* wd    = (const float*)d_in[5];
    const float* bd    = (const float*)d_in[6];
    const float* w2    = (const float*)d_in[7];
    const float* b2    = (const float*)d_in[8];
    float* out = (float*)d_out;

    float* y = (float*)d_ws;                             // (B,T,D) = 16*2560*512 floats (84 MB)
    float* z = y + (size_t)B_SZ * T_LEN * D_CH;          // (T,B,D) = same size

    k1_gemm_glu<<<dim3(640, 8), 256, 0, stream>>>(utt, rc, w1, b1, y);
    k2_dw_utt <<<dim3(32, 8, 16), 256, 0, stream>>>(y, cache, wd, bd, z);
    k2_dw_rc  <<<dim3(64, 16, 2), 256, 0, stream>>>(y, wd, bd, z);
    k4_cache  <<<dim3(960), 256, 0, stream>>>(y, out);
    k3_gemm2  <<<dim3(640, 8), 256, 0, stream>>>(z, w2, b2, out);
}

// Round 2
// 390.940 us; speedup vs baseline: 2.5690x; 2.5690x over previous
//
#include <hip/hip_runtime.h>
#include <math.h>

#define B_SZ 16
#define D_CH 512
#define U_LEN 2048
#define R_LEN 512
#define T_LEN 2560
#define KS 31
#define CS 30

typedef __attribute__((ext_vector_type(8))) short short8;
typedef __attribute__((ext_vector_type(4))) float floatx4;

__device__ __forceinline__ float bf2f(ushort u) {
    unsigned v = (unsigned)u << 16;
    float f; __builtin_memcpy(&f, &v, 4); return f;
}
__device__ __forceinline__ ushort f2bf(float f) {
    unsigned v; __builtin_memcpy(&v, &f, 4);
    v += 0x7fff + ((v >> 16) & 1);
    return (ushort)(v >> 16);
}
__device__ __forceinline__ float sigmoidf_(float x) { return 1.0f / (1.0f + __expf(-x)); }

// async global->LDS, 16B per lane. lds base must be wave-uniform.
__device__ __forceinline__ void gld16(const void* g, void* l) {
    __builtin_amdgcn_global_load_lds((const __attribute__((address_space(1))) void*)g,
                                     (__attribute__((address_space(3))) void*)l, 16, 0, 0);
}

// ---- conversion kernels ----

// w1 (1024x512) -> w1b, w2 (512x512) -> w2b, straight layout copy, float4->bf16x4
__global__ __launch_bounds__(256) void k_conv_w(
    const float* __restrict__ w1, const float* __restrict__ w2,
    ushort* __restrict__ w1b, ushort* __restrict__ w2b)
{
    int t = blockIdx.x * 256 + threadIdx.x;
    const float* src; ushort* dst;
    if (t < 131072) { src = w1; dst = w1b; }
    else            { t -= 131072; src = w2; dst = w2b; }
    float4 v = ((const float4*)src)[t];
    ushort4 o;
    o.x = f2bf(v.x); o.y = f2bf(v.y); o.z = f2bf(v.z); o.w = f2bf(v.w);
    ((ushort4*)dst)[t] = o;
}

// utt (U,B,D) + rc (R,B,D) fp32 -> xb (B,T,D) bf16
__global__ __launch_bounds__(256) void k_conv_x(
    const float* __restrict__ utt, const float* __restrict__ rc, ushort* __restrict__ xb)
{
    int t = blockIdx.x * 256 + threadIdx.x;   // float4 index
    size_t o = (size_t)t * 4;
    int b  = (int)(o / (T_LEN * D_CH));
    int rem = (int)(o % (T_LEN * D_CH));
    int tt = rem >> 9;
    int d  = rem & 511;
    const float* src = (tt < R_LEN) ? rc  + ((size_t)tt * B_SZ + b) * D_CH + d
                                    : utt + ((size_t)(tt - R_LEN) * B_SZ + b) * D_CH + d;
    float4 v = *(const float4*)src;
    ushort4 u;
    u.x = f2bf(v.x); u.y = f2bf(v.y); u.z = f2bf(v.z); u.w = f2bf(v.w);
    *(ushort4*)(xb + o) = u;
}

// cache (B,D,CS) fp32 -> xc (B,CS,D) bf16
__global__ __launch_bounds__(256) void k_conv_cache(
    const float* __restrict__ cache, ushort* __restrict__ xc)
{
    int t = blockIdx.x * 256 + threadIdx.x;   // 245760 total
    int d = t & 511;
    int p = (t >> 9) % CS;
    int b = t / (CS * 512);
    xc[t] = f2bf(cache[((size_t)b * D_CH + d) * CS + p]);
}

// ---- K1: MFMA GEMM (xb 40960x512 @ w1b^T) + GLU -> y bf16 (B,T,D) ----
// block: 256 thr = 4 waves. M-tile 256 (wave w rows w*64..), N-tile 64 output cols.
// Each wave: acc_a[4][4], acc_g[4][4] (64x64 each), fused GLU epilogue.
__global__ __launch_bounds__(256) void k1_mfma(
    const ushort* __restrict__ xb, const ushort* __restrict__ w1b,
    const float* __restrict__ b1, ushort* __restrict__ y)
{
    __shared__ __attribute__((aligned(16))) ushort sA[256 * 32];
    __shared__ __attribute__((aligned(16))) ushort sBa[64 * 32];
    __shared__ __attribute__((aligned(16))) ushort sBg[64 * 32];
    const int tid = threadIdx.x;
    const int w = tid >> 6, lane = tid & 63;
    const int q0 = blockIdx.x * 256;
    const int n0 = blockIdx.y * 64;
    const int col = lane & 15, quad = lane >> 4;

    floatx4 acc_a[4][4], acc_g[4][4];
    #pragma unroll
    for (int i = 0; i < 4; ++i)
        #pragma unroll
        for (int j = 0; j < 4; ++j) { acc_a[i][j] = 0.f; acc_g[i][j] = 0.f; }

    const int sB_s = w * 64 + lane;
    const int sB_r = sB_s >> 2, sB_h = sB_s & 3;

    for (int kc = 0; kc < 512; kc += 32) {
        __syncthreads();
        #pragma unroll
        for (int j = 0; j < 4; ++j) {
            int s = (w * 4 + j) * 64 + lane;
            gld16(xb + (size_t)(q0 + (s >> 2)) * 512 + kc + (s & 3) * 8,
                  &sA[(w * 4 + j) * 512]);
        }
        gld16(w1b + (size_t)(n0 + sB_r) * 512 + kc + sB_h * 8, &sBa[w * 512]);
        gld16(w1b + (size_t)(512 + n0 + sB_r) * 512 + kc + sB_h * 8, &sBg[w * 512]);
        __syncthreads();

        short8 af[4], ba[4], bg[4];
        #pragma unroll
        for (int i = 0; i < 4; ++i)
            af[i] = *(const short8*)&sA[(w * 64 + i * 16 + col) * 32 + quad * 8];
        #pragma unroll
        for (int j = 0; j < 4; ++j) {
            ba[j] = *(const short8*)&sBa[(j * 16 + col) * 32 + quad * 8];
            bg[j] = *(const short8*)&sBg[(j * 16 + col) * 32 + quad * 8];
        }
        #pragma unroll
        for (int i = 0; i < 4; ++i)
            #pragma unroll
            for (int j = 0; j < 4; ++j) {
                acc_a[i][j] = __builtin_amdgcn_mfma_f32_16x16x32_bf16(af[i], ba[j], acc_a[i][j], 0, 0, 0);
                acc_g[i][j] = __builtin_amdgcn_mfma_f32_16x16x32_bf16(af[i], bg[j], acc_g[i][j], 0, 0, 0);
            }
    }

    #pragma unroll
    for (int j = 0; j < 4; ++j) {
        float bia = b1[n0 + j * 16 + col];
        float big = b1[512 + n0 + j * 16 + col];
        #pragma unroll
        for (int i = 0; i < 4; ++i) {
            #pragma unroll
            for (int r = 0; r < 4; ++r) {
                int row = q0 + w * 64 + i * 16 + quad * 4 + r;
                float a = acc_a[i][j][r] + bia;
                float g = acc_g[i][j][r] + big;
                float v = a * sigmoidf_(g);
                y[(size_t)row * 512 + n0 + j * 16 + col] = f2bf(v);
            }
        }
    }
}

// ---- K2: depthwise conv over utterance path + swish, y bf16 -> z bf16 (T,B,D) ----
__global__ __launch_bounds__(256) void k2_dw_utt(
    const ushort* __restrict__ y, const ushort* __restrict__ xc,
    const float* __restrict__ wd, const float* __restrict__ bd, ushort* __restrict__ z)
{
    __shared__ __attribute__((aligned(16))) ushort sy[64 * 97]; // [dl][p]
    __shared__ float sw[64 * 31];
    const int tid = threadIdx.x;
    const int u0 = blockIdx.x * 64;
    const int d0 = blockIdx.y * 64;
    const int b  = blockIdx.z;

    for (int idx = tid; idx < 94 * 8; idx += 256) {
        int r  = idx >> 3;   // p-local 0..93
        int c8 = idx & 7;    // d-octet
        int p  = u0 + r;
        int dg = d0 + c8 * 8;
        const ushort* src = (p < CS) ? xc + ((size_t)b * CS + p) * 512 + dg
                                     : y + ((size_t)b * T_LEN + (R_LEN - CS + p)) * 512 + dg;
        ushort tmp[8];
        *(int4*)tmp = *(const int4*)src;
        #pragma unroll
        for (int j = 0; j < 8; ++j) sy[(c8 * 8 + j) * 97 + r] = tmp[j];
    }
    for (int idx = tid; idx < 64 * 31; idx += 256) {
        int d = idx / 31, k = idx - d * 31;
        sw[d * 31 + k] = wd[(size_t)(d0 + d) * KS + k];
    }
    __syncthreads();

    const int dl   = tid & 63;
    const int useg = (tid >> 6) * 16;
    float win[46];
    #pragma unroll
    for (int p = 0; p < 46; ++p) win[p] = bf2f(sy[dl * 97 + useg + p]);
    float bias = bd[d0 + dl];
    float acc[16];
    #pragma unroll
    for (int i = 0; i < 16; ++i) acc[i] = bias;
    for (int k = 0; k < 31; ++k) {
        float w = sw[dl * 31 + k];
        #pragma unroll
        for (int i = 0; i < 16; ++i) acc[i] = fmaf(w, win[k + i], acc[i]);
    }
    #pragma unroll
    for (int i = 0; i < 16; ++i) {
        float v = acc[i];
        v = v * sigmoidf_(v - 1.0f);
        int u = u0 + useg + i;
        z[((size_t)(R_LEN + u) * B_SZ + b) * D_CH + d0 + dl] = f2bf(v);
    }
}

// ---- K2rc: right-context chunked depthwise conv + swish -> z bf16 ----
__global__ __launch_bounds__(256) void k2_dw_rc(
    const ushort* __restrict__ y, const float* __restrict__ wd, const float* __restrict__ bd,
    ushort* __restrict__ z)
{
    __shared__ __attribute__((aligned(16))) ushort sy[38 * 256]; // [frame][d_local]
    const int tid = threadIdx.x;
    const int i  = blockIdx.x;           // chunk 0..63
    const int b  = blockIdx.y;
    const int dbase = blockIdx.z * 256;

    for (int idx = tid; idx < 38 * 32; idx += 256) {
        int r  = idx >> 5;   // frame 0..37
        int c8 = idx & 31;
        int t = (r < CS) ? (R_LEN + 32 * i + 2 + r) : (8 * i + (r - CS));
        *(int4*)&sy[r * 256 + c8 * 8] =
            *(const int4*)(y + ((size_t)b * T_LEN + t) * 512 + dbase + c8 * 8);
    }
    __syncthreads();

    const int dd = dbase + tid;
    float wr[31];
    #pragma unroll
    for (int k = 0; k < 31; ++k) wr[k] = wd[(size_t)dd * KS + k];
    float bias = bd[dd];
    #pragma unroll
    for (int j = 0; j < 8; ++j) {
        float acc = bias;
        #pragma unroll
        for (int k = 0; k < 31; ++k) acc = fmaf(wr[k], bf2f(sy[(j + k) * 256 + tid]), acc);
        float v = acc * sigmoidf_(acc - 1.0f);
        z[((size_t)(i * 8 + j) * B_SZ + b) * D_CH + dd] = f2bf(v);
    }
}

// ---- K3: MFMA GEMM (z 40960x512 @ w2b^T) + bias -> scattered fp32 outputs ----
__global__ __launch_bounds__(256) void k3_mfma(
    const ushort* __restrict__ zb, const ushort* __restrict__ w2b,
    const float* __restrict__ b2, float* __restrict__ out)
{
    __shared__ __attribute__((aligned(16))) ushort sA[256 * 32];
    __shared__ __attribute__((aligned(16))) ushort sB[64 * 32];
    const int tid = threadIdx.x;
    const int w = tid >> 6, lane = tid & 63;
    const int q0 = blockIdx.x * 256;
    const int n0 = blockIdx.y * 64;
    const int col = lane & 15, quad = lane >> 4;

    floatx4 acc[4][4];
    #pragma unroll
    for (int i = 0; i < 4; ++i)
        #pragma unroll
        for (int j = 0; j < 4; ++j) acc[i][j] = 0.f;

    const int sB_s = w * 64 + lane;
    const int sB_r = sB_s >> 2, sB_h = sB_s & 3;

    for (int kc = 0; kc < 512; kc += 32) {
        __syncthreads();
        #pragma unroll
        for (int j = 0; j < 4; ++j) {
            int s = (w * 4 + j) * 64 + lane;
            gld16(zb + (size_t)(q0 + (s >> 2)) * 512 + kc + (s & 3) * 8,
                  &sA[(w * 4 + j) * 512]);
        }
        gld16(w2b + (size_t)(n0 + sB_r) * 512 + kc + sB_h * 8, &sB[w * 512]);
        __syncthreads();

        short8 af[4], bf[4];
        #pragma unroll
        for (int i = 0; i < 4; ++i)
            af[i] = *(const short8*)&sA[(w * 64 + i * 16 + col) * 32 + quad * 8];
        #pragma unroll
        for (int j = 0; j < 4; ++j)
            bf[j] = *(const short8*)&sB[(j * 16 + col) * 32 + quad * 8];
        #pragma unroll
        for (int i = 0; i < 4; ++i)
            #pragma unroll
            for (int j = 0; j < 4; ++j)
                acc[i][j] = __builtin_amdgcn_mfma_f32_16x16x32_bf16(af[i], bf[j], acc[i][j], 0, 0, 0);
    }

    #pragma unroll
    for (int j = 0; j < 4; ++j) {
        float bb = b2[n0 + j * 16 + col];
        #pragma unroll
        for (int i = 0; i < 4; ++i) {
            #pragma unroll
            for (int r = 0; r < 4; ++r) {
                int q = q0 + w * 64 + i * 16 + quad * 4 + r;
                float v = acc[i][j][r] + bb;
                size_t off = (q < 8192) ? (size_t)16777216 + (size_t)q * 512
                                        : (size_t)(q - 8192) * 512;
                out[off + n0 + j * 16 + col] = v;
            }
        }
    }
}

// ---- K4: new_cache = y frames t=2530..2559 -> out (B,D,CS) fp32 ----
__global__ __launch_bounds__(256) void k4_cache(const ushort* __restrict__ y, float* __restrict__ out)
{
    int tid = blockIdx.x * 256 + threadIdx.x;  // 16*30*512
    int d = tid & 511;
    int j = (tid >> 9) % CS;
    int b = tid / (CS * 512);
    float v = bf2f(y[((size_t)b * T_LEN + (2530 + j)) * 512 + d]);
    out[(size_t)20971520 + ((size_t)b * D_CH + d) * CS + j] = v;
}

extern "C" void kernel_launch(void* const* d_in, const int* in_sizes, int n_in,
                              void* d_out, int out_size, void* d_ws, size_t ws_size,
                              hipStream_t stream)
{
    const float* utt   = (const float*)d_in[0];
    const float* rc    = (const float*)d_in[1];
    const float* cache = (const float*)d_in[2];
    const float* w1    = (const float*)d_in[3];
    const float* b1    = (const float*)d_in[4];
    const float* wd    = (const float*)d_in[5];
    const float* bd    = (const float*)d_in[6];
    const float* w2    = (const float*)d_in[7];
    const float* b2    = (const float*)d_in[8];
    float* out = (float*)d_out;

    ushort* xb  = (ushort*)d_ws;                 // 20971520 bf16 (B,T,D)
    ushort* y   = xb  + (size_t)20971520;        // 20971520 bf16 (B,T,D)
    ushort* zb  = y   + (size_t)20971520;        // 20971520 bf16 (T,B,D)
    ushort* w1b = zb  + (size_t)20971520;        // 524288
    ushort* w2b = w1b + (size_t)524288;          // 262144
    ushort* xc  = w2b + (size_t)262144;          // 245760 bf16 (B,CS,D)

    k_conv_w    <<<dim3(768),        256, 0, stream>>>(w1, w2, w1b, w2b);
    k_conv_x    <<<dim3(20480),      256, 0, stream>>>(utt, rc, xb);
    k_conv_cache<<<dim3(960),        256, 0, stream>>>(cache, xc);
    k1_mfma     <<<dim3(160, 8),     256, 0, stream>>>(xb, w1b, b1, y);
    k2_dw_utt   <<<dim3(32, 8, 16),  256, 0, stream>>>(y, xc, wd, bd, zb);
    k2_dw_rc    <<<dim3(64, 16, 2),  256, 0, stream>>>(y, wd, bd, zb);
    k4_cache    <<<dim3(960),        256, 0, stream>>>(y, out);
    k3_mfma     <<<dim3(160, 8),     256, 0, stream>>>(zb, w2b, b2, out);
}